// Round 3
// baseline (837.596 us; speedup 1.0000x reference)
//
#include <hip/hip_runtime.h>
#include <cstdint>
#include <cstddef>

#define HW 16384
#define NEGF (-__builtin_inff())

typedef unsigned short u16;
typedef _Float16 f16;
typedef _Float16 f16x8 __attribute__((ext_vector_type(8)));
typedef float f32x4 __attribute__((ext_vector_type(4)));

// monotone key: float -> unsigned, order-preserving (handles negatives)
__device__ __forceinline__ unsigned fkey(float f) {
  unsigned b = __float_as_uint(f);
  return (b & 0x80000000u) ? ~b : (b | 0x80000000u);
}
__device__ __forceinline__ float funkey(unsigned u) {
  unsigned b = (u & 0x80000000u) ? (u ^ 0x80000000u) : ~u;
  return __uint_as_float(b);
}

// f16 <-> f32
__device__ __forceinline__ float h2f(u16 u) { f16 h; *(u16*)&h = u; return (float)h; }
__device__ __forceinline__ u16 f2h(float f) { f16 h = (f16)f; return *(u16*)&h; }

union i4h8 { int4 i; f16x8 h; };

// ---------------- pack weights: f16, MFMA-fragment order + biases ----------------
// Wp layout: [kchunk=8][ofrag=20][lane=64][j=8] halfs.
// element = W[o = ofrag*16 + (lane&15)][k = kchunk*32 + (lane>>4)*8 + j]
__global__ __launch_bounds__(256) void pack_kernel(
    const float* __restrict__ Wq, const float* __restrict__ bq,
    const float* __restrict__ Wk, const float* __restrict__ bk,
    const float* __restrict__ Wv, const float* __restrict__ bv,
    u16* __restrict__ Wp, float* __restrict__ ball)
{
  int i = blockIdx.x * 256 + threadIdx.x;   // 0..81919
  {
    int chunk = i / 10240;
    int r = i - chunk * 10240;
    int frag = r >> 9;
    int lane = (r >> 3) & 63;
    int j = i & 7;
    int o = frag * 16 + (lane & 15);
    int kk = chunk * 32 + (lane >> 4) * 8 + j;
    float wv_ = (o < 32) ? Wq[o * 256 + kk]
              : (o < 64) ? Wk[(o - 32) * 256 + kk]
                         : Wv[(o - 64) * 256 + kk];
    Wp[i] = f2h(wv_);
  }
  if (i < 320) {
    ball[i] = (i < 32) ? bq[i] : (i < 64) ? bk[i - 32] : bv[i - 64];
  }
}

// ---------------- projections via f16 MFMA ----------------
// outputs: q16,k16 = f16 NHWC [b][p][32c]; v = f16 planar [b][c][p]
// Epilogue: LDS restage so every global store is a full 64B-line write.
__global__ __launch_bounds__(256) void proj_kernel(
    const float* __restrict__ x1, const float* __restrict__ x2,
    const u16* __restrict__ Wp, const float* __restrict__ ball,
    u16* __restrict__ q16, u16* __restrict__ k16, u16* __restrict__ v)
{
  // union region: loop phase = wlds(20480) + xlds0(4096) + xlds1(4096) = 28672
  //               epilogue  = vs2 64x260 halfs (33280) + qks 2x64x36 (9216) = 42496
  __shared__ __align__(16) char smem[42496];
  u16* wlds = (u16*)smem;
  u16* xlds0 = (u16*)(smem + 20480);
  u16* xlds1 = (u16*)(smem + 24576);

  const int t = threadIdx.x;
  const int w = t >> 6, l = t & 63;
  const int l15 = l & 15, l4 = l >> 4;
  const int blk = blockIdx.x;
  const int b = blk >> 8;
  const int p0 = (blk & 255) << 6;

  // accumulators init with bias (bias depends on o only; row = l4*4 + r)
  f32x4 acc[5][4];
#pragma unroll
  for (int f = 0; f < 5; ++f) {
    f32x4 binit;
#pragma unroll
    for (int r = 0; r < 4; ++r)
      binit[r] = ball[(w * 5 + f) * 16 + l4 * 4 + r];
#pragma unroll
    for (int pf = 0; pf < 4; ++pf) acc[f][pf] = binit;
  }

  const float* xp = (w & 1) ? x2 : x1;
  const int ks_l = (w >> 1) * 16 + (l >> 5) * 8;
  const int px_w = (l & 31) * 2;
  char* xdst = (char*)((w & 1) ? xlds1 : xlds0);
  const int kgw = ks_l >> 3;
  const int offA = px_w * 64 + ((kgw ^ (px_w & 3)) << 4);
  const int offB = (px_w + 1) * 64 + ((kgw ^ ((px_w + 1) & 3)) << 4);

  const int prow = l15, kg2 = l4;
  const char* xsrc1 = (const char*)xlds0;
  const char* xsrc2 = (const char*)xlds1;

  for (int ch = 0; ch < 8; ++ch) {
    int4 wreg[5];
#pragma unroll
    for (int r = 0; r < 5; ++r)
      wreg[r] = *(const int4*)((const char*)Wp + ch * 20480 + (r * 256 + t) * 16);
    float2 xv[8];
    {
      size_t gbase = ((size_t)(b * 256 + ch * 32 + ks_l)) * HW + p0 + px_w;
#pragma unroll
      for (int i = 0; i < 8; ++i) xv[i] = *(const float2*)&xp[gbase + (size_t)i * HW];
    }
    __syncthreads();
#pragma unroll
    for (int r = 0; r < 5; ++r)
      *(int4*)((char*)wlds + (r * 256 + t) * 16) = wreg[r];
    {
      union { u16 h[8]; int4 v4; } pk0, pk1;
#pragma unroll
      for (int i = 0; i < 8; ++i) {
        pk0.h[i] = f2h(xv[i].x); pk1.h[i] = f2h(xv[i].y);
      }
      *(int4*)(xdst + offA) = pk0.v4;
      *(int4*)(xdst + offB) = pk1.v4;
    }
    __syncthreads();

    f16x8 af[5];
#pragma unroll
    for (int f = 0; f < 5; ++f)
      af[f] = *(const f16x8*)((const char*)wlds + (((w * 5 + f) * 64 + l) << 4));
    f16x8 bf[4];
#pragma unroll
    for (int pf = 0; pf < 4; ++pf) {
      int row = pf * 16 + prow;
      bf[pf] = *(const f16x8*)(xsrc2 + row * 64 + ((kg2 ^ (row & 3)) << 4));
    }
    if (w == 0) {
#pragma unroll
      for (int f = 2; f < 5; ++f)
#pragma unroll
        for (int pf = 0; pf < 4; ++pf)
          acc[f][pf] = __builtin_amdgcn_mfma_f32_16x16x32_f16(af[f], bf[pf], acc[f][pf], 0, 0, 0);
#pragma unroll
      for (int pf = 0; pf < 4; ++pf) {
        int row = pf * 16 + prow;
        bf[pf] = *(const f16x8*)(xsrc1 + row * 64 + ((kg2 ^ (row & 3)) << 4));
      }
#pragma unroll
      for (int f = 0; f < 2; ++f)
#pragma unroll
        for (int pf = 0; pf < 4; ++pf)
          acc[f][pf] = __builtin_amdgcn_mfma_f32_16x16x32_f16(af[f], bf[pf], acc[f][pf], 0, 0, 0);
    } else {
#pragma unroll
      for (int f = 0; f < 5; ++f)
#pragma unroll
        for (int pf = 0; pf < 4; ++pf)
          acc[f][pf] = __builtin_amdgcn_mfma_f32_16x16x32_f16(af[f], bf[pf], acc[f][pf], 0, 0, 0);
    }
  }

  // ---- epilogue: stage f16 results to LDS, then full-line global writes ----
  __syncthreads();   // all waves done reading wlds/xlds
  u16* vs2 = (u16*)smem;            // [px=64][stride 260] channels 0..255
  u16* qks = (u16*)(smem + 33280);  // [sel=2][px=64][stride 36] (q, k)
#pragma unroll
  for (int f = 0; f < 5; ++f) {
    int of = w * 5 + f;
    if (of >= 4) {
      int cb = (of - 4) * 16 + l4 * 4;
#pragma unroll
      for (int pf = 0; pf < 4; ++pf) {
        ushort4 h4;
        h4.x = f2h(acc[f][pf][0]); h4.y = f2h(acc[f][pf][1]);
        h4.z = f2h(acc[f][pf][2]); h4.w = f2h(acc[f][pf][3]);
        *(ushort4*)&vs2[(pf * 16 + l15) * 260 + cb] = h4;
      }
    } else {
      int ob = (of & 1) * 16 + l4 * 4;
      int selo = (of >> 1) * 2304;
#pragma unroll
      for (int pf = 0; pf < 4; ++pf) {
        ushort4 h4;
        h4.x = f2h(acc[f][pf][0]); h4.y = f2h(acc[f][pf][1]);
        h4.z = f2h(acc[f][pf][2]); h4.w = f2h(acc[f][pf][3]);
        *(ushort4*)&qks[selo + (pf * 16 + l15) * 36 + ob] = h4;
      }
    }
  }
  __syncthreads();
  // v: thread t = channel c, writes its 64-px row (128 B, two full lines)
  {
    const int c = t;
    u16* dst = v + ((size_t)b * 256 + c) * HW + p0;
#pragma unroll
    for (int g8 = 0; g8 < 8; ++g8) {
      union { u16 h[8]; int4 i; } u;
#pragma unroll
      for (int j = 0; j < 8; ++j) u.h[j] = vs2[(g8 * 8 + j) * 260 + c];
      *(int4*)&dst[g8 * 8] = u.i;
    }
  }
  // q,k: threads 0..127 write full 64 B NHWC rows
  if (t < 128) {
    const int sel = t >> 6, px = t & 63;
    const unsigned long long* sp =
        (const unsigned long long*)(qks + sel * 2304 + px * 36);
    u16* dst = (sel ? k16 : q16) + ((size_t)b * HW + p0 + px) * 32;
    union { unsigned long long u[8]; int4 i4[4]; } buf;
#pragma unroll
    for (int j = 0; j < 8; ++j) buf.u[j] = sp[j];
#pragma unroll
    for (int j = 0; j < 4; ++j) *(int4*)&dst[j * 8] = buf.i4[j];
  }
}

// ---------------- spatial transpose 16-bit planar (per 128x128 plane) ----------------
__global__ __launch_bounds__(256) void transpose_b16(
    const u16* __restrict__ in, u16* __restrict__ out)
{
  __shared__ u16 s[32][33];
  const int plane = blockIdx.y;
  const int tw = blockIdx.x & 3, th = blockIdx.x >> 2;
  const u16* ip = in + (size_t)plane * HW;
  u16* op = out + (size_t)plane * HW;
  const int lx = threadIdx.x & 31, ly = threadIdx.x >> 5;
  const int r0 = th << 5, c0 = tw << 5;
#pragma unroll
  for (int r = 0; r < 4; ++r) s[ly + 8 * r][lx] = ip[(r0 + ly + 8 * r) * 128 + c0 + lx];
  __syncthreads();
#pragma unroll
  for (int r = 0; r < 4; ++r) op[(c0 + ly + 8 * r) * 128 + r0 + lx] = s[lx][ly + 8 * r];
}

// ---------------- NHWC 64B-granule spatial transpose: [b][h][w][32] -> [b][w][h][32] ----
__global__ __launch_bounds__(256) void transpose_c32(
    const u16* __restrict__ in, u16* __restrict__ out)
{
  const int b = blockIdx.y;
  const int tw = blockIdx.x & 7, th = blockIdx.x >> 3;
  const int lw = threadIdx.x & 15, lh = threadIdx.x >> 4;
  const int h = th * 16 + lh, wc = tw * 16 + lw;
  const u16* src = in + ((size_t)b * HW + h * 128 + wc) * 32;
  u16* dst = out + ((size_t)b * HW + wc * 128 + h) * 32;
  int4 v0 = *(const int4*)&src[0];
  int4 v1 = *(const int4*)&src[8];
  int4 v2 = *(const int4*)&src[16];
  int4 v3 = *(const int4*)&src[24];
  *(int4*)&dst[0] = v0;  *(int4*)&dst[8] = v1;
  *(int4*)&dst[16] = v2; *(int4*)&dst[24] = v3;
}

// ---------------- stats pass: exact top-64 threshold + (m, l) per row ----------------
// inputs f16 NHWC tiles: qp/kp = [b][po][row][32c], 8KB per (b,po)
__global__ __launch_bounds__(256) void stats_kernel(
    const u16* __restrict__ qp, const u16* __restrict__ kp,
    float* __restrict__ thr_out, float* __restrict__ m_out, float* __restrict__ l_out,
    int diag)
{
  __shared__ float q_s[32][132];
  __shared__ float k_s[32][132];
  __shared__ float e_s[32][132];
  const int t = threadIdx.x;
  const int po = blockIdx.x, b = blockIdx.y;

  const u16* qt = qp + (size_t)(b * 128 + po) * 128 * 32;
  const u16* kt = kp + (size_t)(b * 128 + po) * 128 * 32;
#pragma unroll
  for (int r = 0; r < 2; ++r) {
    int idx = t * 8 + r * 2048;          // pixel-major: idx = h*32 + c
    int h = idx >> 5, c0 = idx & 31;
    i4h8 qv; qv.i = *(const int4*)&qt[idx];
    i4h8 kv; kv.i = *(const int4*)&kt[idx];
#pragma unroll
    for (int j = 0; j < 8; ++j) {
      q_s[c0 + j][h] = (float)qv.h[j];
      k_s[c0 + j][h] = (float)kv.h[j];
    }
  }
  __syncthreads();

  const int hh = t >> 3;
  const int gg0 = (t & 7) << 4;
  const int wv = t >> 6, ln = t & 63;

  for (int h0 = 0; h0 < 128; h0 += 32) {
    float acc[16];
#pragma unroll
    for (int j = 0; j < 16; ++j) acc[j] = 0.0f;
#pragma unroll
    for (int c = 0; c < 32; ++c) {
      float qv = q_s[c][h0 + hh];
      float4 kv[4];
      kv[0] = *(const float4*)&k_s[c][gg0];
      kv[1] = *(const float4*)&k_s[c][gg0 + 4];
      kv[2] = *(const float4*)&k_s[c][gg0 + 8];
      kv[3] = *(const float4*)&k_s[c][gg0 + 12];
#pragma unroll
      for (int j4 = 0; j4 < 4; ++j4) {
        acc[j4 * 4 + 0] = fmaf(qv, kv[j4].x, acc[j4 * 4 + 0]);
        acc[j4 * 4 + 1] = fmaf(qv, kv[j4].y, acc[j4 * 4 + 1]);
        acc[j4 * 4 + 2] = fmaf(qv, kv[j4].z, acc[j4 * 4 + 2]);
        acc[j4 * 4 + 3] = fmaf(qv, kv[j4].w, acc[j4 * 4 + 3]);
      }
    }
    if (diag) {
      int h = h0 + hh;
#pragma unroll
      for (int j = 0; j < 16; ++j)
        if (gg0 + j == h) acc[j] = NEGF;
    }
#pragma unroll
    for (int j4 = 0; j4 < 4; ++j4)
      *(float4*)&e_s[hh][gg0 + j4 * 4] =
          make_float4(acc[j4 * 4 + 0], acc[j4 * 4 + 1], acc[j4 * 4 + 2], acc[j4 * 4 + 3]);
    __syncthreads();

    for (int rr = 0; rr < 8; ++rr) {
      int row = wv * 8 + rr;
      float e0 = e_s[row][ln], e1 = e_s[row][ln + 64];
      unsigned u0 = fkey(e0), u1 = fkey(e1);
      unsigned uthr = 0u;
      for (int bit = 31; bit >= 0; --bit) {
        unsigned cand = uthr | (1u << bit);
        int cnt = __popcll(__ballot(u0 >= cand)) + __popcll(__ballot(u1 >= cand));
        if (cnt >= 64) uthr = cand;
      }
      unsigned um = u0 > u1 ? u0 : u1;
#pragma unroll
      for (int off = 32; off; off >>= 1) {
        unsigned o = __shfl_xor(um, off);
        um = um > o ? um : o;
      }
      float m = funkey(um);
      float s = ((u0 >= uthr) ? __expf(e0 - m) : 0.0f) +
                ((u1 >= uthr) ? __expf(e1 - m) : 0.0f);
#pragma unroll
      for (int off = 32; off; off >>= 1) s += __shfl_xor(s, off);
      if (ln == 0) {
        size_t idx = ((size_t)b * 128 + po) * 128 + h0 + row;
        thr_out[idx] = __uint_as_float(uthr);
        m_out[idx] = m;
        l_out[idx] = s;
      }
    }
    __syncthreads();
  }
}

// ---------------- fused output pass, MFMA ----------------
// block = (po, b), 512 threads (8 waves). Phase 1: E = q k^T. Phase 1.5:
// threshold/exp -> att f16 (swizzled LDS). Phase 2: acc = att x V (V B-frags
// prefetched from global at start). Epilogue: LDS restage -> full-line f16
// stores, written IN PLACE over this block's V rows (safe: reads done).
template <int DIAG>
__global__ __launch_bounds__(512) void out_mfma(
    const u16* __restrict__ q16, const u16* __restrict__ k16, const u16* __restrict__ vp,
    const float* __restrict__ thr_own, const float* __restrict__ m_own, const float* __restrict__ l_own,
    const float* __restrict__ m_oth, const float* __restrict__ l_oth,
    u16* __restrict__ outp)
{
  __shared__ __align__(16) char smem[50688];
  u16* q_s   = (u16*)smem;             // 8 KB [i][c]
  u16* k_s   = (u16*)(smem + 8192);    // 8 KB [j][c]
  u16* att_s = (u16*)(smem + 16384);   // 32 KB [i][swizzled slots]
  float* m_s = (float*)(smem + 49152);
  float* il_s = (float*)(smem + 49664);
  unsigned* ut_s = (unsigned*)(smem + 50176);
  u16* stage = (u16*)smem;             // epilogue overlay [cslot=128][132]

  const int t = threadIdx.x;
  const int w = t >> 6, l = t & 63;
  const int l15 = l & 15, l4 = l >> 4;
  const int po = blockIdx.x, b = blockIdx.y;

  // ---- prefetch V B-fragments: c = w*32 + nf*16 + l15, j = ks*32 + l4*8 ----
  int4 vld[2][4];
#pragma unroll
  for (int nf = 0; nf < 2; ++nf) {
    int c = w * 32 + nf * 16 + l15;
    size_t vb = ((size_t)(b * 256 + c) * 128 + po) * 128 + l4 * 8;
#pragma unroll
    for (int ks = 0; ks < 4; ++ks)
      vld[nf][ks] = *(const int4*)&vp[vb + ks * 32];
  }

  // ---- stage q,k tiles (8KB each, 512 x 16B) ----
  {
    const u16* qt = q16 + (size_t)(b * 128 + po) * 128 * 32;
    const u16* kt = k16 + (size_t)(b * 128 + po) * 128 * 32;
    *(int4*)&q_s[t * 8] = *(const int4*)&qt[t * 8];
    *(int4*)&k_s[t * 8] = *(const int4*)&kt[t * 8];
  }
  // ---- combine stats ----
  if (t < 128) {
    size_t own = ((size_t)b * 128 + po) * 128 + t;
    size_t oth = ((size_t)b * 128 + t) * 128 + po;
    float ma = m_own[own], la = l_own[own];
    float mb = m_oth[oth], lb = l_oth[oth];
    float m = fmaxf(ma, mb);
    float lsum = la * __expf(ma - m) + lb * __expf(mb - m);
    m_s[t] = m;
    il_s[t] = 1.0f / lsum;
    ut_s[t] = __float_as_uint(thr_own[own]);
  }
  __syncthreads();

  // ---- phase 1: E rows i in [w*16, w*16+16) ----
  f32x4 eacc[8];
#pragma unroll
  for (int nj = 0; nj < 8; ++nj) eacc[nj] = (f32x4){0.f, 0.f, 0.f, 0.f};
  {
    f16x8 aq = *(const f16x8*)&q_s[(w * 16 + l15) * 32 + l4 * 8];
#pragma unroll
    for (int nj = 0; nj < 8; ++nj) {
      f16x8 bk = *(const f16x8*)&k_s[(nj * 16 + l15) * 32 + l4 * 8];
      eacc[nj] = __builtin_amdgcn_mfma_f32_16x16x32_f16(aq, bk, eacc[nj], 0, 0, 0);
    }
  }

  // ---- phase 1.5: threshold/exp -> att f16 (slot = (j>>3) ^ (i&15)) ----
  {
    float mm[4], ii[4];
    unsigned uu[4];
#pragma unroll
    for (int r = 0; r < 4; ++r) {
      int i = w * 16 + l4 * 4 + r;
      mm[r] = m_s[i]; ii[r] = il_s[i]; uu[r] = ut_s[i];
    }
#pragma unroll
    for (int nj = 0; nj < 8; ++nj) {
      int j = nj * 16 + l15;
#pragma unroll
      for (int r = 0; r < 4; ++r) {
        int i = w * 16 + l4 * 4 + r;
        float e = eacc[nj][r];
        float a;
        if (DIAG && i == j) {
          a = 0.0f;
        } else {
          unsigned ue = fkey(e);
          a = (ue >= uu[r]) ? __expf(e - mm[r]) * ii[r] : 0.0f;
        }
        att_s[i * 128 + ((((j >> 3) ^ (i & 15)) << 3) | (j & 7))] = f2h(a);
      }
    }
  }
  __syncthreads();

  // ---- phase 2: out[i][c] = sum_j att[i][j] V[c][j]; wave owns 32 c ----
  f32x4 acc[8][2];
#pragma unroll
  for (int mi = 0; mi < 8; ++mi)
#pragma unroll
    for (int nf = 0; nf < 2; ++nf) acc[mi][nf] = (f32x4){0.f, 0.f, 0.f, 0.f};

#pragma unroll
  for (int ks = 0; ks < 4; ++ks) {
    i4h8 bv0, bv1;
    bv0.i = vld[0][ks];
    bv1.i = vld[1][ks];
#pragma unroll
    for (int mi = 0; mi < 8; ++mi) {
      int i = mi * 16 + l15;
      int s = (ks * 4 + l4) ^ (i & 15);
      f16x8 pa = *(const f16x8*)&att_s[i * 128 + s * 8];
      acc[mi][0] = __builtin_amdgcn_mfma_f32_16x16x32_f16(pa, bv0.h, acc[mi][0], 0, 0, 0);
      acc[mi][1] = __builtin_amdgcn_mfma_f32_16x16x32_f16(pa, bv1.h, acc[mi][1], 0, 0, 0);
    }
  }

  // ---- epilogue: two rounds of LDS restage + full-line stores ----
  __syncthreads();   // att_s reads complete; stage may overwrite
#pragma unroll
  for (int rd = 0; rd < 2; ++rd) {
    if ((w >> 2) == rd) {
#pragma unroll
      for (int mi = 0; mi < 8; ++mi)
#pragma unroll
        for (int nf = 0; nf < 2; ++nf) {
          int cslot = (w & 3) * 32 + nf * 16 + l15;
          int i = mi * 16 + l4 * 4;
          ushort4 h4;
          h4.x = f2h(acc[mi][nf][0]); h4.y = f2h(acc[mi][nf][1]);
          h4.z = f2h(acc[mi][nf][2]); h4.w = f2h(acc[mi][nf][3]);
          *(ushort4*)&stage[cslot * 132 + i] = h4;
        }
    }
    __syncthreads();
    {
      const int cslot = t >> 2, seg = t & 3;
      const int c = rd * 128 + cslot;
      const unsigned long long* sp =
          (const unsigned long long*)(stage + cslot * 132 + seg * 32);
      u16* dst = outp + ((size_t)(b * 256 + c) * 128 + po) * 128 + seg * 32;
      union { unsigned long long u[8]; int4 i4[4]; } buf;
#pragma unroll
      for (int j = 0; j < 8; ++j) buf.u[j] = sp[j];
#pragma unroll
      for (int j = 0; j < 4; ++j) *(int4*)&dst[j * 8] = buf.i4[j];
    }
    if (rd == 0) __syncthreads();
  }
}

// ---------------- final combine: out = g*(accW + accH^T) + x1 ----------------
// accW = f16 [plane][h][w], accH = f16 [plane][w][h]; 64x64 tiles.
__global__ __launch_bounds__(256) void addT2_kernel(
    const u16* __restrict__ accW, const u16* __restrict__ accH,
    const float* __restrict__ x1, const float* __restrict__ gptr,
    float* __restrict__ out)
{
  __shared__ __align__(16) u16 hs[64][72];
  const int plane = blockIdx.y;
  const int th = blockIdx.x >> 1, tw = blockIdx.x & 1;
  const int h0 = th * 64, w0 = tw * 64;
  const float g = gptr[0];
  const int t = threadIdx.x;

  // load accH tile rows [w][h]: thread = (w row, 32B segment)
  {
    int wr = t >> 2, seg = t & 3;
    const u16* src = accH + (size_t)plane * HW + (size_t)(w0 + wr) * 128 + h0 + seg * 16;
    int4 a = *(const int4*)&src[0];
    int4 b2 = *(const int4*)&src[8];
    *(int4*)&hs[wr][seg * 16] = a;
    *(int4*)&hs[wr][seg * 16 + 8] = b2;
  }
  __syncthreads();

  // combine: thread = (h row, 16-w segment); full-line float4 stores
  const int h = t & 63, wseg = t >> 6;
  size_t rbase = (size_t)plane * HW + (size_t)(h0 + h) * 128 + w0 + wseg * 16;
  const u16* wsrc = accW + rbase;
  const float* xsrc = x1 + rbase;
  float* osrc = out + rbase;
  union { int4 i4[2]; u16 hx[16]; } uw;
  uw.i4[0] = *(const int4*)&wsrc[0];
  uw.i4[1] = *(const int4*)&wsrc[8];
#pragma unroll
  for (int j4 = 0; j4 < 4; ++j4) {
    float4 xv = *(const float4*)&xsrc[j4 * 4];
    float4 o;
    o.x = g * (h2f(uw.hx[j4 * 4 + 0]) + h2f(hs[wseg * 16 + j4 * 4 + 0][h])) + xv.x;
    o.y = g * (h2f(uw.hx[j4 * 4 + 1]) + h2f(hs[wseg * 16 + j4 * 4 + 1][h])) + xv.y;
    o.z = g * (h2f(uw.hx[j4 * 4 + 2]) + h2f(hs[wseg * 16 + j4 * 4 + 2][h])) + xv.z;
    o.w = g * (h2f(uw.hx[j4 * 4 + 3]) + h2f(hs[wseg * 16 + j4 * 4 + 3][h])) + xv.w;
    *(float4*)&osrc[j4 * 4] = o;
  }
}

// ---------------- launch ----------------
// ws (floats): Wp 40960+pad | q16,k16,q16T,k16T f16 4x8MB | stats 3MB | v,vT f16 2x64MB
// accW overwrites v in place (W out pass); accH overwrites vT in place (H out pass).
extern "C" void kernel_launch(void* const* d_in, const int* in_sizes, int n_in,
                              void* d_out, int out_size, void* d_ws, size_t ws_size,
                              hipStream_t stream)
{
  const float* x1 = (const float*)d_in[0];
  const float* x2 = (const float*)d_in[1];
  const float* Wq = (const float*)d_in[2];
  const float* bq = (const float*)d_in[3];
  const float* Wk = (const float*)d_in[4];
  const float* bk = (const float*)d_in[5];
  const float* Wv = (const float*)d_in[6];
  const float* bv = (const float*)d_in[7];
  const float* gm = (const float*)d_in[8];
  float* out = (float*)d_out;
  float* ws = (float*)d_ws;

  u16*   Wp    = (u16*)ws;                  // 81,920 halfs
  float* ball  = ws + 81920;                // 320 f (region padded to 82,304)
  u16*   q16   = (u16*)(ws + 82304);        // 4,194,304 halfs each
  u16*   k16   = q16 + 4194304;
  u16*   q16T  = k16 + 4194304;
  u16*   k16T  = q16T + 4194304;
  float* stats = (float*)(k16T + 4194304);  // 786,432 f
  u16*   v     = (u16*)(stats + 786432);    // 33,554,432 halfs
  u16*   vT    = v + 33554432;              // 33,554,432 halfs

  float* thrH = stats;
  float* mH   = stats + 131072;
  float* lH   = stats + 262144;
  float* thrW = stats + 393216;
  float* mW   = stats + 524288;
  float* lW   = stats + 655360;

  pack_kernel<<<320, 256, 0, stream>>>(Wq, bq, Wk, bk, Wv, bv, Wp, ball);
  proj_kernel<<<2048, 256, 0, stream>>>(x1, x2, Wp, ball, q16, k16, v);
  transpose_b16<<<dim3(16, 2048), 256, 0, stream>>>(v, vT);
  transpose_c32<<<dim3(64, 8), 256, 0, stream>>>(q16, q16T);
  transpose_c32<<<dim3(64, 8), 256, 0, stream>>>(k16, k16T);
  stats_kernel<<<dim3(128, 8), 256, 0, stream>>>(q16T, k16T, thrH, mH, lH, 1);
  stats_kernel<<<dim3(128, 8), 256, 0, stream>>>(q16, k16, thrW, mW, lW, 0);
  // W pass: writes accW f16 in place over v
  out_mfma<0><<<dim3(128, 8), 512, 0, stream>>>(
      q16, k16, v, thrW, mW, lW, mH, lH, v);
  // H pass: writes accH f16 in place over vT
  out_mfma<1><<<dim3(128, 8), 512, 0, stream>>>(
      q16T, k16T, vT, thrH, mH, lH, mW, lW, vT);
  // final combine: out = g*(accW + accH^T) + x1
  addT2_kernel<<<dim3(4, 2048), 256, 0, stream>>>(v, vT, x1, gm, out);
}

// Round 4
// 764.731 us; speedup vs baseline: 1.0953x; 1.0953x over previous
//
#include <hip/hip_runtime.h>
#include <cstdint>
#include <cstddef>

#define HW 16384
#define NEGF (-__builtin_inff())

typedef unsigned short u16;
typedef _Float16 f16;
typedef _Float16 f16x8 __attribute__((ext_vector_type(8)));
typedef float f32x4 __attribute__((ext_vector_type(4)));

// monotone key: float -> unsigned, order-preserving (handles negatives)
__device__ __forceinline__ unsigned fkey(float f) {
  unsigned b = __float_as_uint(f);
  return (b & 0x80000000u) ? ~b : (b | 0x80000000u);
}
__device__ __forceinline__ float funkey(unsigned u) {
  unsigned b = (u & 0x80000000u) ? (u ^ 0x80000000u) : ~u;
  return __uint_as_float(b);
}

// f16 <-> f32
__device__ __forceinline__ float h2f(u16 u) { f16 h; *(u16*)&h = u; return (float)h; }
__device__ __forceinline__ u16 f2h(float f) { f16 h = (f16)f; return *(u16*)&h; }

union i4h8 { int4 i; f16x8 h; };

// ---------------- pack weights: f16, MFMA-fragment order + biases ----------------
// Wp layout: [kchunk=8][ofrag=20][lane=64][j=8] halfs.
// element = W[o = ofrag*16 + (lane&15)][k = kchunk*32 + (lane>>4)*8 + j]
__global__ __launch_bounds__(256) void pack_kernel(
    const float* __restrict__ Wq, const float* __restrict__ bq,
    const float* __restrict__ Wk, const float* __restrict__ bk,
    const float* __restrict__ Wv, const float* __restrict__ bv,
    u16* __restrict__ Wp, float* __restrict__ ball)
{
  int i = blockIdx.x * 256 + threadIdx.x;   // 0..81919
  {
    int chunk = i / 10240;
    int r = i - chunk * 10240;
    int frag = r >> 9;
    int lane = (r >> 3) & 63;
    int j = i & 7;
    int o = frag * 16 + (lane & 15);
    int kk = chunk * 32 + (lane >> 4) * 8 + j;
    float wv_ = (o < 32) ? Wq[o * 256 + kk]
              : (o < 64) ? Wk[(o - 32) * 256 + kk]
                         : Wv[(o - 64) * 256 + kk];
    Wp[i] = f2h(wv_);
  }
  if (i < 320) {
    ball[i] = (i < 32) ? bq[i] : (i < 64) ? bk[i - 32] : bv[i - 64];
  }
}

// ---------------- projections via f16 MFMA ----------------
// outputs: q16,k16 = f16 NHWC [b][p][32c]; v = f16 planar [b][c][p]
// Epilogue: LDS restage; every global store instruction covers full aligned
// 64/128-B granules ACROSS LANES (per-instruction contiguity).
__global__ __launch_bounds__(256) void proj_kernel(
    const float* __restrict__ x1, const float* __restrict__ x2,
    const u16* __restrict__ Wp, const float* __restrict__ ball,
    u16* __restrict__ q16, u16* __restrict__ k16, u16* __restrict__ v)
{
  // loop phase: wlds(20480) + xlds0(4096) + xlds1(4096) = 28672
  // epilogue : vs_half 64x132 halfs (16896) + qks 2x64x40 (10240) = 27136
  __shared__ __align__(16) char smem[28672];
  u16* wlds = (u16*)smem;
  u16* xlds0 = (u16*)(smem + 20480);
  u16* xlds1 = (u16*)(smem + 24576);

  const int t = threadIdx.x;
  const int w = t >> 6, l = t & 63;
  const int l15 = l & 15, l4 = l >> 4;
  const int blk = blockIdx.x;
  const int b = blk >> 8;
  const int p0 = (blk & 255) << 6;

  // accumulators init with bias (bias depends on o only; row = l4*4 + r)
  f32x4 acc[5][4];
#pragma unroll
  for (int f = 0; f < 5; ++f) {
    f32x4 binit;
#pragma unroll
    for (int r = 0; r < 4; ++r)
      binit[r] = ball[(w * 5 + f) * 16 + l4 * 4 + r];
#pragma unroll
    for (int pf = 0; pf < 4; ++pf) acc[f][pf] = binit;
  }

  const float* xp = (w & 1) ? x2 : x1;
  const int ks_l = (w >> 1) * 16 + (l >> 5) * 8;
  const int px_w = (l & 31) * 2;
  char* xdst = (char*)((w & 1) ? xlds1 : xlds0);
  const int kgw = ks_l >> 3;
  const int offA = px_w * 64 + ((kgw ^ (px_w & 3)) << 4);
  const int offB = (px_w + 1) * 64 + ((kgw ^ ((px_w + 1) & 3)) << 4);

  const int prow = l15, kg2 = l4;
  const char* xsrc1 = (const char*)xlds0;
  const char* xsrc2 = (const char*)xlds1;

  for (int ch = 0; ch < 8; ++ch) {
    int4 wreg[5];
#pragma unroll
    for (int r = 0; r < 5; ++r)
      wreg[r] = *(const int4*)((const char*)Wp + ch * 20480 + (r * 256 + t) * 16);
    float2 xv[8];
    {
      size_t gbase = ((size_t)(b * 256 + ch * 32 + ks_l)) * HW + p0 + px_w;
#pragma unroll
      for (int i = 0; i < 8; ++i) xv[i] = *(const float2*)&xp[gbase + (size_t)i * HW];
    }
    __syncthreads();
#pragma unroll
    for (int r = 0; r < 5; ++r)
      *(int4*)((char*)wlds + (r * 256 + t) * 16) = wreg[r];
    {
      union { u16 h[8]; int4 v4; } pk0, pk1;
#pragma unroll
      for (int i = 0; i < 8; ++i) {
        pk0.h[i] = f2h(xv[i].x); pk1.h[i] = f2h(xv[i].y);
      }
      *(int4*)(xdst + offA) = pk0.v4;
      *(int4*)(xdst + offB) = pk1.v4;
    }
    __syncthreads();

    f16x8 af[5];
#pragma unroll
    for (int f = 0; f < 5; ++f)
      af[f] = *(const f16x8*)((const char*)wlds + (((w * 5 + f) * 64 + l) << 4));
    f16x8 bf[4];
#pragma unroll
    for (int pf = 0; pf < 4; ++pf) {
      int row = pf * 16 + prow;
      bf[pf] = *(const f16x8*)(xsrc2 + row * 64 + ((kg2 ^ (row & 3)) << 4));
    }
    if (w == 0) {
#pragma unroll
      for (int f = 2; f < 5; ++f)
#pragma unroll
        for (int pf = 0; pf < 4; ++pf)
          acc[f][pf] = __builtin_amdgcn_mfma_f32_16x16x32_f16(af[f], bf[pf], acc[f][pf], 0, 0, 0);
#pragma unroll
      for (int pf = 0; pf < 4; ++pf) {
        int row = pf * 16 + prow;
        bf[pf] = *(const f16x8*)(xsrc1 + row * 64 + ((kg2 ^ (row & 3)) << 4));
      }
#pragma unroll
      for (int f = 0; f < 2; ++f)
#pragma unroll
        for (int pf = 0; pf < 4; ++pf)
          acc[f][pf] = __builtin_amdgcn_mfma_f32_16x16x32_f16(af[f], bf[pf], acc[f][pf], 0, 0, 0);
    } else {
#pragma unroll
      for (int f = 0; f < 5; ++f)
#pragma unroll
        for (int pf = 0; pf < 4; ++pf)
          acc[f][pf] = __builtin_amdgcn_mfma_f32_16x16x32_f16(af[f], bf[pf], acc[f][pf], 0, 0, 0);
    }
  }

  // ---- epilogue ----
  __syncthreads();   // all waves done with wlds/xlds
  u16* vs_half = (u16*)smem;            // [px=64][stride 132] half of channels
  u16* qks = (u16*)(smem + 16896);      // [sel=2][px=64][stride 40]

  // stage q/k fragments (once)
#pragma unroll
  for (int f = 0; f < 5; ++f) {
    int of = w * 5 + f;
    if (of < 4) {
      int ob = (of & 1) * 16 + l4 * 4;
      int selo = (of >> 1) * 2560;
#pragma unroll
      for (int pf = 0; pf < 4; ++pf) {
        ushort4 h4;
        h4.x = f2h(acc[f][pf][0]); h4.y = f2h(acc[f][pf][1]);
        h4.z = f2h(acc[f][pf][2]); h4.w = f2h(acc[f][pf][3]);
        *(ushort4*)&qks[selo + (pf * 16 + l15) * 40 + ob] = h4;
      }
    }
  }

#pragma unroll
  for (int rd = 0; rd < 2; ++rd) {
    // stage v channels in [rd*128, rd*128+128)
#pragma unroll
    for (int f = 0; f < 5; ++f) {
      int of = w * 5 + f;
      if (of >= 4) {
        int cb = (of - 4) * 16 + l4 * 4;
        if ((cb >> 7) == rd) {
          int cl = cb & 127;
#pragma unroll
          for (int pf = 0; pf < 4; ++pf) {
            ushort4 h4;
            h4.x = f2h(acc[f][pf][0]); h4.y = f2h(acc[f][pf][1]);
            h4.z = f2h(acc[f][pf][2]); h4.w = f2h(acc[f][pf][3]);
            *(ushort4*)&vs_half[(pf * 16 + l15) * 132 + cl] = h4;
          }
        }
      }
    }
    __syncthreads();
    // store v half: per instruction, 8 lanes cover 128 B per channel, 8 ch/wave
#pragma unroll
    for (int n = 0; n < 4; ++n) {
      int cl = n * 32 + (t >> 3);
      int pxo = (t & 7) * 8;
      union { u16 h[8]; int4 i; } u;
#pragma unroll
      for (int j = 0; j < 8; ++j) u.h[j] = vs_half[(pxo + j) * 132 + cl];
      *(int4*)&v[((size_t)b * 256 + rd * 128 + cl) * HW + p0 + pxo] = u.i;
    }
    if (rd == 0) {
      // q,k: per instruction, 16 px-rows x full 64 B (1 KB contiguous)
      if (t < 128) {
        int sel = t >> 6, l2 = t & 63;
        u16* dst16 = sel ? k16 : q16;
#pragma unroll
        for (int r = 0; r < 4; ++r) {
          int px = r * 16 + (l2 >> 2), seg = l2 & 3;
          int4 d = *(const int4*)&qks[sel * 2560 + px * 40 + seg * 8];
          *(int4*)&dst16[((size_t)b * HW + p0 + px) * 32 + seg * 8] = d;
        }
      }
      __syncthreads();   // vs_half reads done before rd=1 restage
    }
  }
}

// ---------------- spatial transpose 16-bit planar (per 128x128 plane) ----------------
__global__ __launch_bounds__(256) void transpose_b16(
    const u16* __restrict__ in, u16* __restrict__ out)
{
  __shared__ u16 s[32][33];
  const int plane = blockIdx.y;
  const int tw = blockIdx.x & 3, th = blockIdx.x >> 2;
  const u16* ip = in + (size_t)plane * HW;
  u16* op = out + (size_t)plane * HW;
  const int lx = threadIdx.x & 31, ly = threadIdx.x >> 5;
  const int r0 = th << 5, c0 = tw << 5;
#pragma unroll
  for (int r = 0; r < 4; ++r) s[ly + 8 * r][lx] = ip[(r0 + ly + 8 * r) * 128 + c0 + lx];
  __syncthreads();
#pragma unroll
  for (int r = 0; r < 4; ++r) op[(c0 + ly + 8 * r) * 128 + r0 + lx] = s[lx][ly + 8 * r];
}

// ---------------- NHWC 64B-granule spatial transpose: [b][h][w][32] -> [b][w][h][32] ----
__global__ __launch_bounds__(256) void transpose_c32(
    const u16* __restrict__ in, u16* __restrict__ out)
{
  const int b = blockIdx.y;
  const int tw = blockIdx.x & 7, th = blockIdx.x >> 3;
  const int lw = threadIdx.x & 15, lh = threadIdx.x >> 4;
  const int h = th * 16 + lh, wc = tw * 16 + lw;
  const u16* src = in + ((size_t)b * HW + h * 128 + wc) * 32;
  u16* dst = out + ((size_t)b * HW + wc * 128 + h) * 32;
  int4 v0 = *(const int4*)&src[0];
  int4 v1 = *(const int4*)&src[8];
  int4 v2 = *(const int4*)&src[16];
  int4 v3 = *(const int4*)&src[24];
  *(int4*)&dst[0] = v0;  *(int4*)&dst[8] = v1;
  *(int4*)&dst[16] = v2; *(int4*)&dst[24] = v3;
}

// ---------------- stats pass: exact top-64 threshold + (m, l) per row ----------------
// inputs f16 NHWC tiles: qp/kp = [b][po][row][32c], 8KB per (b,po)
__global__ __launch_bounds__(256) void stats_kernel(
    const u16* __restrict__ qp, const u16* __restrict__ kp,
    float* __restrict__ thr_out, float* __restrict__ m_out, float* __restrict__ l_out,
    int diag)
{
  __shared__ float q_s[32][132];
  __shared__ float k_s[32][132];
  __shared__ float e_s[32][132];
  const int t = threadIdx.x;
  const int po = blockIdx.x, b = blockIdx.y;

  const u16* qt = qp + (size_t)(b * 128 + po) * 128 * 32;
  const u16* kt = kp + (size_t)(b * 128 + po) * 128 * 32;
#pragma unroll
  for (int r = 0; r < 2; ++r) {
    int idx = t * 8 + r * 2048;          // pixel-major: idx = h*32 + c
    int h = idx >> 5, c0 = idx & 31;
    i4h8 qv; qv.i = *(const int4*)&qt[idx];
    i4h8 kv; kv.i = *(const int4*)&kt[idx];
#pragma unroll
    for (int j = 0; j < 8; ++j) {
      q_s[c0 + j][h] = (float)qv.h[j];
      k_s[c0 + j][h] = (float)kv.h[j];
    }
  }
  __syncthreads();

  const int hh = t >> 3;
  const int gg0 = (t & 7) << 4;
  const int wv = t >> 6, ln = t & 63;

  for (int h0 = 0; h0 < 128; h0 += 32) {
    float acc[16];
#pragma unroll
    for (int j = 0; j < 16; ++j) acc[j] = 0.0f;
#pragma unroll
    for (int c = 0; c < 32; ++c) {
      float qv = q_s[c][h0 + hh];
      float4 kv[4];
      kv[0] = *(const float4*)&k_s[c][gg0];
      kv[1] = *(const float4*)&k_s[c][gg0 + 4];
      kv[2] = *(const float4*)&k_s[c][gg0 + 8];
      kv[3] = *(const float4*)&k_s[c][gg0 + 12];
#pragma unroll
      for (int j4 = 0; j4 < 4; ++j4) {
        acc[j4 * 4 + 0] = fmaf(qv, kv[j4].x, acc[j4 * 4 + 0]);
        acc[j4 * 4 + 1] = fmaf(qv, kv[j4].y, acc[j4 * 4 + 1]);
        acc[j4 * 4 + 2] = fmaf(qv, kv[j4].z, acc[j4 * 4 + 2]);
        acc[j4 * 4 + 3] = fmaf(qv, kv[j4].w, acc[j4 * 4 + 3]);
      }
    }
    if (diag) {
      int h = h0 + hh;
#pragma unroll
      for (int j = 0; j < 16; ++j)
        if (gg0 + j == h) acc[j] = NEGF;
    }
#pragma unroll
    for (int j4 = 0; j4 < 4; ++j4)
      *(float4*)&e_s[hh][gg0 + j4 * 4] =
          make_float4(acc[j4 * 4 + 0], acc[j4 * 4 + 1], acc[j4 * 4 + 2], acc[j4 * 4 + 3]);
    __syncthreads();

    for (int rr = 0; rr < 8; ++rr) {
      int row = wv * 8 + rr;
      float e0 = e_s[row][ln], e1 = e_s[row][ln + 64];
      unsigned u0 = fkey(e0), u1 = fkey(e1);
      unsigned uthr = 0u;
      for (int bit = 31; bit >= 0; --bit) {
        unsigned cand = uthr | (1u << bit);
        int cnt = __popcll(__ballot(u0 >= cand)) + __popcll(__ballot(u1 >= cand));
        if (cnt >= 64) uthr = cand;
      }
      unsigned um = u0 > u1 ? u0 : u1;
#pragma unroll
      for (int off = 32; off; off >>= 1) {
        unsigned o = __shfl_xor(um, off);
        um = um > o ? um : o;
      }
      float m = funkey(um);
      float s = ((u0 >= uthr) ? __expf(e0 - m) : 0.0f) +
                ((u1 >= uthr) ? __expf(e1 - m) : 0.0f);
#pragma unroll
      for (int off = 32; off; off >>= 1) s += __shfl_xor(s, off);
      if (ln == 0) {
        size_t idx = ((size_t)b * 128 + po) * 128 + h0 + row;
        thr_out[idx] = __uint_as_float(uthr);
        m_out[idx] = m;
        l_out[idx] = s;
      }
    }
    __syncthreads();
  }
}

// ---------------- fused output pass, MFMA ----------------
// block = (po, b), 512 threads (8 waves). Phase 1: E = q k^T. Phase 1.5:
// threshold/exp -> att f16 (swizzled LDS). Phase 2: acc = att x V (V B-frags
// prefetched from global). Epilogue: LDS restage -> per-instruction 256-B
// contiguous stores, written IN PLACE over this block's V rows.
template <int DIAG>
__global__ __launch_bounds__(512) void out_mfma(
    const u16* __restrict__ q16, const u16* __restrict__ k16, const u16* __restrict__ vp,
    const float* __restrict__ thr_own, const float* __restrict__ m_own, const float* __restrict__ l_own,
    const float* __restrict__ m_oth, const float* __restrict__ l_oth,
    u16* __restrict__ outp)
{
  __shared__ __align__(16) char smem[50688];
  u16* q_s   = (u16*)smem;             // 8 KB [i][c]
  u16* k_s   = (u16*)(smem + 8192);    // 8 KB [j][c]
  u16* att_s = (u16*)(smem + 16384);   // 32 KB [i][swizzled slots]
  float* m_s = (float*)(smem + 49152);
  float* il_s = (float*)(smem + 49664);
  unsigned* ut_s = (unsigned*)(smem + 50176);
  u16* stage = (u16*)smem;             // epilogue overlay [cslot=128][136]

  const int t = threadIdx.x;
  const int w = t >> 6, l = t & 63;
  const int l15 = l & 15, l4 = l >> 4;
  const int po = blockIdx.x, b = blockIdx.y;

  // ---- prefetch V B-fragments: c = w*32 + nf*16 + l15, j = ks*32 + l4*8 ----
  int4 vld[2][4];
#pragma unroll
  for (int nf = 0; nf < 2; ++nf) {
    int c = w * 32 + nf * 16 + l15;
    size_t vb = ((size_t)(b * 256 + c) * 128 + po) * 128 + l4 * 8;
#pragma unroll
    for (int ks = 0; ks < 4; ++ks)
      vld[nf][ks] = *(const int4*)&vp[vb + ks * 32];
  }

  // ---- stage q,k tiles (8KB each, 512 x 16B) ----
  {
    const u16* qt = q16 + (size_t)(b * 128 + po) * 128 * 32;
    const u16* kt = k16 + (size_t)(b * 128 + po) * 128 * 32;
    *(int4*)&q_s[t * 8] = *(const int4*)&qt[t * 8];
    *(int4*)&k_s[t * 8] = *(const int4*)&kt[t * 8];
  }
  // ---- combine stats ----
  if (t < 128) {
    size_t own = ((size_t)b * 128 + po) * 128 + t;
    size_t oth = ((size_t)b * 128 + t) * 128 + po;
    float ma = m_own[own], la = l_own[own];
    float mb = m_oth[oth], lb = l_oth[oth];
    float m = fmaxf(ma, mb);
    float lsum = la * __expf(ma - m) + lb * __expf(mb - m);
    m_s[t] = m;
    il_s[t] = 1.0f / lsum;
    ut_s[t] = __float_as_uint(thr_own[own]);
  }
  __syncthreads();

  // ---- phase 1: E rows i in [w*16, w*16+16) ----
  f32x4 eacc[8];
#pragma unroll
  for (int nj = 0; nj < 8; ++nj) eacc[nj] = (f32x4){0.f, 0.f, 0.f, 0.f};
  {
    f16x8 aq = *(const f16x8*)&q_s[(w * 16 + l15) * 32 + l4 * 8];
#pragma unroll
    for (int nj = 0; nj < 8; ++nj) {
      f16x8 bk = *(const f16x8*)&k_s[(nj * 16 + l15) * 32 + l4 * 8];
      eacc[nj] = __builtin_amdgcn_mfma_f32_16x16x32_f16(aq, bk, eacc[nj], 0, 0, 0);
    }
  }

  // ---- phase 1.5: threshold/exp -> att f16 (slot = (j>>3) ^ (i&15)) ----
  {
    float mm[4], ii[4];
    unsigned uu[4];
#pragma unroll
    for (int r = 0; r < 4; ++r) {
      int i = w * 16 + l4 * 4 + r;
      mm[r] = m_s[i]; ii[r] = il_s[i]; uu[r] = ut_s[i];
    }
#pragma unroll
    for (int nj = 0; nj < 8; ++nj) {
      int j = nj * 16 + l15;
#pragma unroll
      for (int r = 0; r < 4; ++r) {
        int i = w * 16 + l4 * 4 + r;
        float e = eacc[nj][r];
        float a;
        if (DIAG && i == j) {
          a = 0.0f;
        } else {
          unsigned ue = fkey(e);
          a = (ue >= uu[r]) ? __expf(e - mm[r]) * ii[r] : 0.0f;
        }
        att_s[i * 128 + ((((j >> 3) ^ (i & 15)) << 3) | (j & 7))] = f2h(a);
      }
    }
  }
  __syncthreads();

  // ---- phase 2: out[i][c] = sum_j att[i][j] V[c][j]; wave owns 32 c ----
  f32x4 acc[8][2];
#pragma unroll
  for (int mi = 0; mi < 8; ++mi)
#pragma unroll
    for (int nf = 0; nf < 2; ++nf) acc[mi][nf] = (f32x4){0.f, 0.f, 0.f, 0.f};

#pragma unroll
  for (int ks = 0; ks < 4; ++ks) {
    i4h8 bv0, bv1;
    bv0.i = vld[0][ks];
    bv1.i = vld[1][ks];
#pragma unroll
    for (int mi = 0; mi < 8; ++mi) {
      int i = mi * 16 + l15;
      int s = (ks * 4 + l4) ^ (i & 15);
      f16x8 pa = *(const f16x8*)&att_s[i * 128 + s * 8];
      acc[mi][0] = __builtin_amdgcn_mfma_f32_16x16x32_f16(pa, bv0.h, acc[mi][0], 0, 0, 0);
      acc[mi][1] = __builtin_amdgcn_mfma_f32_16x16x32_f16(pa, bv1.h, acc[mi][1], 0, 0, 0);
    }
  }

  // ---- epilogue: 2 stage rounds; stores are 256-B contiguous per 16 lanes ----
  __syncthreads();   // att_s reads complete; stage may overwrite
#pragma unroll
  for (int rd = 0; rd < 2; ++rd) {
    if ((w >> 2) == rd) {
#pragma unroll
      for (int mi = 0; mi < 8; ++mi)
#pragma unroll
        for (int nf = 0; nf < 2; ++nf) {
          int cslot = (w & 3) * 32 + nf * 16 + l15;
          int i = mi * 16 + l4 * 4;
          ushort4 h4;
          h4.x = f2h(acc[mi][nf][0]); h4.y = f2h(acc[mi][nf][1]);
          h4.z = f2h(acc[mi][nf][2]); h4.w = f2h(acc[mi][nf][3]);
          *(ushort4*)&stage[cslot * 136 + i] = h4;
        }
    }
    __syncthreads();
#pragma unroll
    for (int n = 0; n < 4; ++n) {
      int cslot = n * 32 + (t >> 4);
      int io = (t & 15) * 8;
      int4 d = *(const int4*)&stage[cslot * 136 + io];
      *(int4*)&outp[((size_t)(b * 256 + rd * 128 + cslot) * 128 + po) * 128 + io] = d;
    }
    if (rd == 0) __syncthreads();
  }
}

// ---------------- final combine: out = g*(accW + accH^T) + x1 ----------------
// accW = f16 [plane][h][w], accH = f16 [plane][w][h]; 64x64 tiles.
// Stores: 16 lanes cover 256 B contiguous per h-row per instruction.
__global__ __launch_bounds__(256) void addT2_kernel(
    const u16* __restrict__ accW, const u16* __restrict__ accH,
    const float* __restrict__ x1, const float* __restrict__ gptr,
    float* __restrict__ out)
{
  __shared__ __align__(16) u16 hs[64][72];
  const int plane = blockIdx.y;
  const int th = blockIdx.x >> 1, tw = blockIdx.x & 1;
  const int h0 = th * 64, w0 = tw * 64;
  const float g = gptr[0];
  const int t = threadIdx.x;

  // load accH tile rows [w][h]
  {
    int wr = t >> 2, seg = t & 3;
    const u16* src = accH + (size_t)plane * HW + (size_t)(w0 + wr) * 128 + h0 + seg * 16;
    int4 a = *(const int4*)&src[0];
    int4 b2 = *(const int4*)&src[8];
    *(int4*)&hs[wr][seg * 16] = a;
    *(int4*)&hs[wr][seg * 16 + 8] = b2;
  }
  __syncthreads();

  // combine: 4 rounds; per round thread handles (h = n*16 + t>>4, 4 w floats)
#pragma unroll
  for (int n = 0; n < 4; ++n) {
    int h = n * 16 + (t >> 4);
    int wo = (t & 15) * 4;
    size_t rbase = (size_t)plane * HW + (size_t)(h0 + h) * 128 + w0 + wo;
    ushort4 aw = *(const ushort4*)&accW[rbase];
    float4 xv = *(const float4*)&x1[rbase];
    float4 o;
    o.x = g * (h2f(aw.x) + h2f(hs[wo + 0][h])) + xv.x;
    o.y = g * (h2f(aw.y) + h2f(hs[wo + 1][h])) + xv.y;
    o.z = g * (h2f(aw.z) + h2f(hs[wo + 2][h])) + xv.z;
    o.w = g * (h2f(aw.w) + h2f(hs[wo + 3][h])) + xv.w;
    *(float4*)&out[rbase] = o;
  }
}

// ---------------- launch ----------------
// ws (floats): Wp 40960+pad | q16,k16,q16T,k16T f16 4x8MB | stats 3MB | v,vT f16 2x64MB
// accW overwrites v in place (W out pass); accH overwrites vT in place (H out pass).
extern "C" void kernel_launch(void* const* d_in, const int* in_sizes, int n_in,
                              void* d_out, int out_size, void* d_ws, size_t ws_size,
                              hipStream_t stream)
{
  const float* x1 = (const float*)d_in[0];
  const float* x2 = (const float*)d_in[1];
  const float* Wq = (const float*)d_in[2];
  const float* bq = (const float*)d_in[3];
  const float* Wk = (const float*)d_in[4];
  const float* bk = (const float*)d_in[5];
  const float* Wv = (const float*)d_in[6];
  const float* bv = (const float*)d_in[7];
  const float* gm = (const float*)d_in[8];
  float* out = (float*)d_out;
  float* ws = (float*)d_ws;

  u16*   Wp    = (u16*)ws;                  // 81,920 halfs
  float* ball  = ws + 81920;                // 320 f (region padded to 82,304)
  u16*   q16   = (u16*)(ws + 82304);        // 4,194,304 halfs each
  u16*   k16   = q16 + 4194304;
  u16*   q16T  = k16 + 4194304;
  u16*   k16T  = q16T + 4194304;
  float* stats = (float*)(k16T + 4194304);  // 786,432 f
  u16*   v     = (u16*)(stats + 786432);    // 33,554,432 halfs
  u16*   vT    = v + 33554432;              // 33,554,432 halfs

  float* thrH = stats;
  float* mH   = stats + 131072;
  float* lH   = stats + 262144;
  float* thrW = stats + 393216;
  float* mW   = stats + 524288;
  float* lW   = stats + 655360;

  pack_kernel<<<320, 256, 0, stream>>>(Wq, bq, Wk, bk, Wv, bv, Wp, ball);
  proj_kernel<<<2048, 256, 0, stream>>>(x1, x2, Wp, ball, q16, k16, v);
  transpose_b16<<<dim3(16, 2048), 256, 0, stream>>>(v, vT);
  transpose_c32<<<dim3(64, 8), 256, 0, stream>>>(q16, q16T);
  transpose_c32<<<dim3(64, 8), 256, 0, stream>>>(k16, k16T);
  stats_kernel<<<dim3(128, 8), 256, 0, stream>>>(q16T, k16T, thrH, mH, lH, 1);
  stats_kernel<<<dim3(128, 8), 256, 0, stream>>>(q16, k16, thrW, mW, lW, 0);
  // W pass: writes accW f16 in place over v
  out_mfma<0><<<dim3(128, 8), 512, 0, stream>>>(
      q16, k16, v, thrW, mW, lW, mH, lH, v);
  // H pass: writes accH f16 in place over vT
  out_mfma<1><<<dim3(128, 8), 512, 0, stream>>>(
      q16T, k16T, vT, thrH, mH, lH, mW, lW, vT);
  // final combine: out = g*(accW + accH^T) + x1
  addT2_kernel<<<dim3(4, 2048), 256, 0, stream>>>(v, vT, x1, gm, out);
}